// Round 6
// baseline (19507.393 us; speedup 1.0000x reference)
//
#include <hip/hip_runtime.h>

#define S 1024
#define NOBS 4096
#define TSTEPS 8192
#define NLAUNCH 256  // launched WGs; all co-resident => some XCD hosts >= NEED
#define NEED 32      // participating WGs (all on one XCD)
#define COLS 32      // output columns per participating WG
#define NTHR 512     // 8 waves
#define NWAVE 8
#define CPW 4        // columns per wave
#define ESC_SPINS 16384  // sc0-poll spins before escalating to agent scope

#define AGENT __HIP_MEMORY_SCOPE_AGENT

typedef __attribute__((ext_vector_type(2))) _Float16 half2v;
typedef __attribute__((ext_vector_type(2))) unsigned short ushort2v;
typedef __attribute__((ext_vector_type(4))) unsigned int uint4v;

__device__ __forceinline__ float wmaxred(float v) {
#pragma unroll
  for (int off = 32; off > 0; off >>= 1) v = fmaxf(v, __shfl_xor(v, off, 64));
  return v;
}
__device__ __forceinline__ float wsumred(float v) {
#pragma unroll
  for (int off = 32; off > 0; off >>= 1) v += __shfl_xor(v, off, 64);
  return v;
}

// L2-coherent (XCD-scope) primitives: sc0 = bypass L1, hit/write the XCD's L2.
// NOTE "=&v" early-clobber: without it the result pair may alias the address
// pair and the first load destroys the address (round-5 hang).
__device__ __forceinline__ unsigned long long load_u64_l2(const unsigned long long* a) {
  unsigned long long w;
  asm volatile("global_load_dwordx2 %0, %1, off sc0\n\ts_waitcnt vmcnt(0)"
               : "=&v"(w) : "v"(a) : "memory");
  return w;
}
__device__ __forceinline__ void store_u128_l2(unsigned* p, uint4v v) {
  asm volatile("global_store_dwordx4 %0, %1, off sc0" ::"v"(p), "v"(v) : "memory");
}
// Self-validating poll with hang insurance: after ESC_SPINS fruitless sc0
// spins, fall back (permanently, via esc) to agent-scope loads.
__device__ __forceinline__ unsigned long long poll_u64(const unsigned long long* a,
                                                       unsigned tag, bool& esc) {
  const unsigned long long pat =
      ((unsigned long long)tag << 16) | ((unsigned long long)tag << 48);
  const unsigned long long msk = 0xFFFF0000FFFF0000ULL;
  unsigned long long w;
  int spins = 0;
  for (;;) {
    w = esc ? __hip_atomic_load(a, __ATOMIC_RELAXED, AGENT) : load_u64_l2(a);
    if ((w & msk) == pat) return w;
    if (!esc && ++spins >= ESC_SPINS) esc = true;
  }
}

__device__ __forceinline__ float f16v(unsigned short b) {
  return (float)__builtin_bit_cast(_Float16, b);
}
__device__ __forceinline__ unsigned short f16b(float f) {
  return __builtin_bit_cast(unsigned short, (_Float16)f);
}

// One-time: Et[j][i] = exp(trans[i][j])  (transposed, fp16) via LDS tile transpose.
__global__ void prep_E(const float* __restrict__ trans, _Float16* __restrict__ Et) {
  __shared__ float tile[32][33];
  const int tx = threadIdx.x, ty = threadIdx.y;
  const int bi = blockIdx.y, bj = blockIdx.x;
  tile[ty][tx] = trans[(size_t)(bi * 32 + ty) * S + bj * 32 + tx];
  __syncthreads();
  Et[(size_t)(bj * 32 + ty) * S + bi * 32 + tx] = (_Float16)__expf(tile[tx][ty]);
}

// One-time: r0 = start + emit[:, obs[0]] packed {tag=0|fp16}; election state reset.
__global__ void hmm_init(const int* __restrict__ obs, const float* __restrict__ start,
                         const float* __restrict__ emit, unsigned* rbuf, int* ctrl) {
  const int tid = threadIdx.x;  // 1024 threads
  const float r = start[tid] + emit[(size_t)tid * NOBS + obs[0]];
  rbuf[tid] = (unsigned)f16b(r);  // tag 0 in hi16
  if (tid < 8) ctrl[tid] = 0;     // per-XCD arrival counters
  if (tid == 8) ctrl[8] = -1;     // winner XCD
}

__global__ __launch_bounds__(NTHR) void hmm_main(
    const int* __restrict__ obs, const float* __restrict__ emit,
    const _Float16* __restrict__ Et, unsigned* rbuf, int* ctrl,
    float* __restrict__ out) {
  __shared__ unsigned sp[2][S / 2];  // p packed half2, double-buffered (4 KB)
  __shared__ float wred[NWAVE];
  __shared__ int s_rank;
  const int tid = threadIdx.x;
  const int lane = tid & 63;
  const int wave = tid >> 6;

  // ---- election: the 32 first-arriving WGs on one XCD participate ----
  if (tid == 0) {
    int x;
    asm volatile("s_getreg_b32 %0, hwreg(HW_REG_XCC_ID)" : "=s"(x));
    x &= 7;
    const int r = atomicAdd(&ctrl[x], 1);  // device-scope
    int wnr = -2;
    if (r == NEED - 1) atomicCAS(&ctrl[8], -1, x);
    if (r < NEED) {
      while ((wnr = __hip_atomic_load(&ctrl[8], __ATOMIC_RELAXED, AGENT)) == -1)
        __builtin_amdgcn_s_sleep(8);
    }
    s_rank = (wnr == x) ? r : -1;
  }
  __syncthreads();
  const int rank = s_rank;
  if (rank < 0) return;

  const int c0 = rank * COLS + wave * CPW;  // this wave's 4 output columns
  bool esc = false;

  // E fragments in registers, packed fp16: er[c][k] = E[src pair (64k+lane)][col c0+c]
  half2v er[CPW][8];
#pragma unroll
  for (int c = 0; c < CPW; ++c)
#pragma unroll
    for (int k = 0; k < 8; ++k)
      er[c][k] = *(const half2v*)(Et + (size_t)(c0 + c) * S + k * 128 + lane * 2);

  unsigned long long* const b0 = (unsigned long long*)rbuf;        // even t
  unsigned long long* const b1 = (unsigned long long*)(rbuf + S);  // odd t

  // Preamble: fresh m = max(r_0), identical in every thread/WG.
  {
    const unsigned long long w = poll_u64(b0 + tid, 0u, esc);
    const float wm =
        wmaxred(fmaxf(f16v((unsigned short)w), f16v((unsigned short)(w >> 32))));
    if (lane == 0) wred[wave] = wm;
  }
  __syncthreads();
  float m = wred[0];
#pragma unroll
  for (int k = 1; k < NWAVE; ++k) m = fmaxf(m, wred[k]);

  double c = 0.0;  // accumulated scale offset; identical in every thread
  for (int t = 1; t < TSTEPS; ++t) {
    // emit gather for this step (lanes 0..3), issued before the poll
    const int ot = obs[t];
    float e = 0.f;
    if (lane < CPW) e = emit[(size_t)(c0 + lane) * NOBS + ot];

    // poll own u64 of r_{t-1} (slots 2*tid, 2*tid+1) from the XCD-local L2
    const unsigned long long w =
        poll_u64(((t & 1) ? b0 : b1) + tid, (unsigned)(t - 1), esc);
    const float va = f16v((unsigned short)w);
    const float vb = f16v((unsigned short)(w >> 32));
    half2v ph;
    ph[0] = (_Float16)__expf(va - m);
    ph[1] = (_Float16)__expf(vb - m);
    sp[t & 1][tid] = __builtin_bit_cast(unsigned, ph);
    __syncthreads();  // the only barrier per step

    // dot: 8 conflict-free LDS b32 reads, 32 fdot2; track packed max(p) alongside
    const unsigned* pb = sp[t & 1];
    float a0 = 0.f, a1 = 0.f, a2 = 0.f, a3 = 0.f;
    ushort2v mx = {0, 0};
#pragma unroll
    for (int k = 0; k < 8; ++k) {
      const unsigned pw = pb[k * 64 + lane];
      mx = __builtin_elementwise_max(mx, __builtin_bit_cast(ushort2v, pw));
      const half2v pv = __builtin_bit_cast(half2v, pw);
      a0 = __builtin_amdgcn_fdot2(pv, er[0][k], a0, false);
      a1 = __builtin_amdgcn_fdot2(pv, er[1][k], a1, false);
      a2 = __builtin_amdgcn_fdot2(pv, er[2][k], a2, false);
      a3 = __builtin_amdgcn_fdot2(pv, er[3][k], a3, false);
    }
    a0 = wsumred(a0);
    a1 = wsumred(a1);
    a2 = wsumred(a2);
    a3 = wsumred(a3);

    // publish 4 columns as one 16B sc0 store (per-u32 tags make tearing safe)
    const float e0 = __shfl(e, 0), e1 = __shfl(e, 1), e2 = __shfl(e, 2), e3 = __shfl(e, 3);
    if (lane == 0) {
      const unsigned tg = (unsigned)t << 16;
      uint4v o;
      o.x = tg | f16b(__logf(a0) + e0);
      o.y = tg | f16b(__logf(a1) + e1);
      o.z = tg | f16b(__logf(a2) + e2);
      o.w = tg | f16b(__logf(a3) + e3);
      store_u128_l2(rbuf + (t & 1) * S + c0, o);
    }

    // off the critical path: scale bookkeeping and next step's stale m
    c += (double)m;
#pragma unroll
    for (int off = 32; off > 0; off >>= 1) {
      const unsigned o2 = __shfl_xor(__builtin_bit_cast(unsigned, mx), off, 64);
      mx = __builtin_elementwise_max(mx, __builtin_bit_cast(ushort2v, o2));
    }
    const unsigned short ms = mx[0] > mx[1] ? mx[0] : mx[1];  // positive fp16: bit order = value order
    m += __logf(f16v(ms));  // m = max(r_{t-1}); bit-identical in every wave/WG
  }

  // Final logsumexp over r_{T-1} by rank 0, wave 0 (8 u64/lane covers all 1024).
  if (rank == 0 && wave == 0) {
    const unsigned long long* src = b1 + lane * 8;  // 8191 is odd
    float v[16];
#pragma unroll
    for (int j = 0; j < 8; ++j) {
      const unsigned long long w = poll_u64(&src[j], TSTEPS - 1, esc);
      v[2 * j] = f16v((unsigned short)w);
      v[2 * j + 1] = f16v((unsigned short)(w >> 32));
    }
    float g = -1e30f;
#pragma unroll
    for (int j = 0; j < 16; ++j) g = fmaxf(g, v[j]);
    g = wmaxred(g);
    float s = 0.f;
#pragma unroll
    for (int j = 0; j < 16; ++j) s += __expf(v[j] - g);
    s = wsumred(s);
    if (lane == 0) out[0] = (float)(c + (double)g + (double)__logf(s));
  }
}

extern "C" void kernel_launch(void* const* d_in, const int* in_sizes, int n_in,
                              void* d_out, int out_size, void* d_ws, size_t ws_size,
                              hipStream_t stream) {
  const int* obs = (const int*)d_in[0];
  const float* start = (const float*)d_in[1];
  const float* trans = (const float*)d_in[2];
  const float* emit = (const float*)d_in[3];

  // ws: 0: rbuf[2][1024] u32 (8 KB) | 12288: ctrl[9] int | 16384: Et 1024*1024 fp16 (2 MB)
  unsigned* rbuf = (unsigned*)d_ws;
  int* ctrl = (int*)((char*)d_ws + 12288);
  _Float16* Et = (_Float16*)((char*)d_ws + 16384);

  prep_E<<<dim3(32, 32), dim3(32, 32), 0, stream>>>(trans, Et);
  hmm_init<<<1, S, 0, stream>>>(obs, start, emit, rbuf, ctrl);
  hmm_main<<<NLAUNCH, NTHR, 0, stream>>>(obs, emit, Et, rbuf, ctrl, (float*)d_out);
}

// Round 7
// 18608.340 us; speedup vs baseline: 1.0483x; 1.0483x over previous
//
#include <hip/hip_runtime.h>

#define S 1024
#define NOBS 4096
#define TSTEPS 8192
#define NLAUNCH 256  // launched WGs; all co-resident => some XCD hosts >= NEED
#define NEED 32      // participating WGs (all on one XCD)
#define COLS 32      // output columns per participating WG
#define NTHR 512     // 8 waves
#define NWAVE 8
#define CPW 4        // columns per wave
#define ESC_SPINS 16384  // sc0-poll spins before escalating to agent scope

#define AGENT __HIP_MEMORY_SCOPE_AGENT

typedef __attribute__((ext_vector_type(2))) _Float16 half2v;
typedef __attribute__((ext_vector_type(2))) unsigned short ushort2v;
typedef __attribute__((ext_vector_type(4))) unsigned int uint4v;

__device__ __forceinline__ float wmaxred(float v) {
#pragma unroll
  for (int off = 32; off > 0; off >>= 1) v = fmaxf(v, __shfl_xor(v, off, 64));
  return v;
}
__device__ __forceinline__ float wsumred(float v) {
#pragma unroll
  for (int off = 32; off > 0; off >>= 1) v += __shfl_xor(v, off, 64);
  return v;
}

// L2-coherent (XCD-scope) primitives: sc0 = bypass L1, hit/write the XCD's L2.
// "=&v" early-clobber: result must not alias the address pair (round-5 hang).
__device__ __forceinline__ unsigned long long load_u64_l2(const unsigned long long* a) {
  unsigned long long w;
  asm volatile("global_load_dwordx2 %0, %1, off sc0\n\ts_waitcnt vmcnt(0)"
               : "=&v"(w) : "v"(a) : "memory");
  return w;
}
__device__ __forceinline__ void store_u128_l2(unsigned* p, uint4v v) {
  asm volatile("global_store_dwordx4 %0, %1, off sc0" ::"v"(p), "v"(v) : "memory");
}
// Self-validating poll with backoff + hang insurance. s_sleep(1) (~64 cyc)
// between failed checks cuts the read flood on the producer's cachelines;
// after ESC_SPINS fruitless spins fall back permanently to agent scope.
__device__ __forceinline__ unsigned long long poll_u64(const unsigned long long* a,
                                                       unsigned tag, bool& esc) {
  const unsigned long long pat =
      ((unsigned long long)tag << 16) | ((unsigned long long)tag << 48);
  const unsigned long long msk = 0xFFFF0000FFFF0000ULL;
  unsigned long long w;
  int spins = 0;
  for (;;) {
    w = esc ? __hip_atomic_load(a, __ATOMIC_RELAXED, AGENT) : load_u64_l2(a);
    if ((w & msk) == pat) return w;
    __builtin_amdgcn_s_sleep(1);
    if (!esc && ++spins >= ESC_SPINS) esc = true;
  }
}

__device__ __forceinline__ float f16v(unsigned short b) {
  return (float)__builtin_bit_cast(_Float16, b);
}
__device__ __forceinline__ unsigned short f16b(float f) {
  return __builtin_bit_cast(unsigned short, (_Float16)f);
}

// One-time: Et[j][i] = exp(trans[i][j])  (transposed, fp16) via LDS tile transpose.
__global__ void prep_E(const float* __restrict__ trans, _Float16* __restrict__ Et) {
  __shared__ float tile[32][33];
  const int tx = threadIdx.x, ty = threadIdx.y;
  const int bi = blockIdx.y, bj = blockIdx.x;
  tile[ty][tx] = trans[(size_t)(bi * 32 + ty) * S + bj * 32 + tx];
  __syncthreads();
  Et[(size_t)(bj * 32 + ty) * S + bi * 32 + tx] = (_Float16)__expf(tile[tx][ty]);
}

// One-time: r0 = start + emit[:, obs[0]] packed {tag=0|fp16}; election state reset.
__global__ void hmm_init(const int* __restrict__ obs, const float* __restrict__ start,
                         const float* __restrict__ emit, unsigned* rbuf, int* ctrl) {
  const int tid = threadIdx.x;  // 1024 threads
  const float r = start[tid] + emit[(size_t)tid * NOBS + obs[0]];
  rbuf[tid] = (unsigned)f16b(r);  // tag 0 in hi16
  if (tid < 8) ctrl[tid] = 0;     // per-XCD arrival counters
  if (tid == 8) ctrl[8] = -1;     // winner XCD
}

__global__ __launch_bounds__(NTHR) void hmm_main(
    const int* __restrict__ obs, const float* __restrict__ emit,
    const _Float16* __restrict__ Et, unsigned* rbuf, int* ctrl,
    float* __restrict__ out) {
  __shared__ unsigned sp[2][S / 2];  // p packed half2, double-buffered (4 KB)
  __shared__ float wred[NWAVE];
  __shared__ int s_rank;
  const int tid = threadIdx.x;
  const int lane = tid & 63;
  const int wave = tid >> 6;

  // ---- election: the 32 first-arriving WGs on one XCD participate ----
  if (tid == 0) {
    int x;
    asm volatile("s_getreg_b32 %0, hwreg(HW_REG_XCC_ID)" : "=s"(x));
    x &= 7;
    const int r = atomicAdd(&ctrl[x], 1);  // device-scope
    int wnr = -2;
    if (r == NEED - 1) atomicCAS(&ctrl[8], -1, x);
    if (r < NEED) {
      while ((wnr = __hip_atomic_load(&ctrl[8], __ATOMIC_RELAXED, AGENT)) == -1)
        __builtin_amdgcn_s_sleep(8);
    }
    s_rank = (wnr == x) ? r : -1;
  }
  __syncthreads();
  const int rank = s_rank;
  if (rank < 0) return;

  const int c0 = rank * COLS + wave * CPW;  // this wave's 4 output columns
  bool esc = false;

  // E fragments in registers, packed fp16: er[c][k] = E[src pair (64k+lane)][col c0+c]
  half2v er[CPW][8];
#pragma unroll
  for (int c = 0; c < CPW; ++c)
#pragma unroll
    for (int k = 0; k < 8; ++k)
      er[c][k] = *(const half2v*)(Et + (size_t)(c0 + c) * S + k * 128 + lane * 2);

  // ---- emit/obs prefetch pipeline (8 steps per fetch, double-buffered) ----
  // Lane L carries e for step-offset (L>>2)&7, column c0+(L&3). One vector
  // load per wave per 8 steps; values consumed 8..16 steps after issue, so
  // HBM-miss latency (single-XCD L2 thrash) is fully hidden.
  const int pfoff = (lane >> 2) & 7;   // step offset within group
  const int pfcol = c0 + (lane & 3);   // emit row
  float curE, nxtE;
  {
    const int o1 = obs[1 + pfoff];           // group [1,9)
    curE = emit[(size_t)pfcol * NOBS + o1];
    const int o2 = obs[9 + pfoff];           // group [9,17)
    nxtE = emit[(size_t)pfcol * NOBS + o2];
  }

  unsigned long long* const b0 = (unsigned long long*)rbuf;        // even t
  unsigned long long* const b1 = (unsigned long long*)(rbuf + S);  // odd t

  // Preamble: fresh m = max(r_0), identical in every thread/WG.
  {
    const unsigned long long w = poll_u64(b0 + tid, 0u, esc);
    const float wm =
        wmaxred(fmaxf(f16v((unsigned short)w), f16v((unsigned short)(w >> 32))));
    if (lane == 0) wred[wave] = wm;
  }
  __syncthreads();
  float m = wred[0];
#pragma unroll
  for (int k = 1; k < NWAVE; ++k) m = fmaxf(m, wred[k]);

  double c = 0.0;  // accumulated scale offset; identical in every thread
  for (int t = 1; t < TSTEPS; ++t) {
    const int s = (t - 1) & 7;
    if (s == 0 && t > 1) {  // rotate prefetch buffers, fetch group [t+8, t+16)
      curE = nxtE;
      const int oi = obs[min(t + 8 + pfoff, TSTEPS - 1)];
      nxtE = emit[(size_t)pfcol * NOBS + oi];
    }
    // this step's emit values for cols c0..c0+3 — pure shuffles, no memory
    const float e0 = __shfl(curE, 4 * s + 0);
    const float e1 = __shfl(curE, 4 * s + 1);
    const float e2 = __shfl(curE, 4 * s + 2);
    const float e3 = __shfl(curE, 4 * s + 3);

    // poll own u64 of r_{t-1} (slots 2*tid, 2*tid+1) from the XCD-local L2
    const unsigned long long w =
        poll_u64(((t & 1) ? b0 : b1) + tid, (unsigned)(t - 1), esc);
    const float va = f16v((unsigned short)w);
    const float vb = f16v((unsigned short)(w >> 32));
    half2v ph;
    ph[0] = (_Float16)__expf(va - m);
    ph[1] = (_Float16)__expf(vb - m);
    sp[t & 1][tid] = __builtin_bit_cast(unsigned, ph);
    __syncthreads();  // the only barrier per step

    // dot: 8 conflict-free LDS b32 reads, 32 fdot2; track packed max(p) alongside
    const unsigned* pb = sp[t & 1];
    float a0 = 0.f, a1 = 0.f, a2 = 0.f, a3 = 0.f;
    ushort2v mx = {0, 0};
#pragma unroll
    for (int k = 0; k < 8; ++k) {
      const unsigned pw = pb[k * 64 + lane];
      mx = __builtin_elementwise_max(mx, __builtin_bit_cast(ushort2v, pw));
      const half2v pv = __builtin_bit_cast(half2v, pw);
      a0 = __builtin_amdgcn_fdot2(pv, er[0][k], a0, false);
      a1 = __builtin_amdgcn_fdot2(pv, er[1][k], a1, false);
      a2 = __builtin_amdgcn_fdot2(pv, er[2][k], a2, false);
      a3 = __builtin_amdgcn_fdot2(pv, er[3][k], a3, false);
    }
    a0 = wsumred(a0);
    a1 = wsumred(a1);
    a2 = wsumred(a2);
    a3 = wsumred(a3);

    // publish: distribute the 4 logs across lanes 0..3, gather, one 16B sc0 store
    {
      const float av = (lane & 1) ? ((lane & 2) ? a3 : a1) : ((lane & 2) ? a2 : a0);
      const float ev = (lane & 1) ? ((lane & 2) ? e3 : e1) : ((lane & 2) ? e2 : e0);
      const unsigned myw = ((unsigned)t << 16) | f16b(__logf(av) + ev);
      const unsigned w1 = __shfl(myw, 1), w2 = __shfl(myw, 2), w3 = __shfl(myw, 3);
      if (lane == 0) {
        uint4v o;
        o.x = myw; o.y = w1; o.z = w2; o.w = w3;
        store_u128_l2(rbuf + (t & 1) * S + c0, o);
      }
    }

    // off the critical path: scale bookkeeping and next step's stale m
    c += (double)m;
#pragma unroll
    for (int off = 32; off > 0; off >>= 1) {
      const unsigned o2 = __shfl_xor(__builtin_bit_cast(unsigned, mx), off, 64);
      mx = __builtin_elementwise_max(mx, __builtin_bit_cast(ushort2v, o2));
    }
    const unsigned short ms = mx[0] > mx[1] ? mx[0] : mx[1];  // positive fp16: bit order = value order
    m += __logf(f16v(ms));  // m = max(r_{t-1}); bit-identical in every wave/WG
  }

  // Final logsumexp over r_{T-1} by rank 0, wave 0 (8 u64/lane covers all 1024).
  if (rank == 0 && wave == 0) {
    const unsigned long long* src = b1 + lane * 8;  // 8191 is odd
    float v[16];
#pragma unroll
    for (int j = 0; j < 8; ++j) {
      const unsigned long long w = poll_u64(&src[j], TSTEPS - 1, esc);
      v[2 * j] = f16v((unsigned short)w);
      v[2 * j + 1] = f16v((unsigned short)(w >> 32));
    }
    float g = -1e30f;
#pragma unroll
    for (int j = 0; j < 16; ++j) g = fmaxf(g, v[j]);
    g = wmaxred(g);
    float s = 0.f;
#pragma unroll
    for (int j = 0; j < 16; ++j) s += __expf(v[j] - g);
    s = wsumred(s);
    if (lane == 0) out[0] = (float)(c + (double)g + (double)__logf(s));
  }
}

extern "C" void kernel_launch(void* const* d_in, const int* in_sizes, int n_in,
                              void* d_out, int out_size, void* d_ws, size_t ws_size,
                              hipStream_t stream) {
  const int* obs = (const int*)d_in[0];
  const float* start = (const float*)d_in[1];
  const float* trans = (const float*)d_in[2];
  const float* emit = (const float*)d_in[3];

  // ws: 0: rbuf[2][1024] u32 (8 KB) | 12288: ctrl[9] int | 16384: Et 1024*1024 fp16 (2 MB)
  unsigned* rbuf = (unsigned*)d_ws;
  int* ctrl = (int*)((char*)d_ws + 12288);
  _Float16* Et = (_Float16*)((char*)d_ws + 16384);

  prep_E<<<dim3(32, 32), dim3(32, 32), 0, stream>>>(trans, Et);
  hmm_init<<<1, S, 0, stream>>>(obs, start, emit, rbuf, ctrl);
  hmm_main<<<NLAUNCH, NTHR, 0, stream>>>(obs, emit, Et, rbuf, ctrl, (float*)d_out);
}

// Round 8
// 17125.325 us; speedup vs baseline: 1.1391x; 1.0866x over previous
//
#include <hip/hip_runtime.h>

#define S 1024
#define NOBS 4096
#define TSTEPS 8192
#define NLAUNCH 256  // launched WGs; all co-resident => some XCD hosts >= NEED
#define NEED 16      // participating WGs (all on one XCD)
#define COLS 64      // output columns per participating WG
#define NTHR 512     // 8 waves
#define NWAVE 8
#define CPW 8        // columns per wave
#define ESC_SPINS 16384  // sc0-poll spins before escalating to agent scope

#define AGENT __HIP_MEMORY_SCOPE_AGENT

typedef __attribute__((ext_vector_type(2))) _Float16 half2v;
typedef __attribute__((ext_vector_type(2))) unsigned short ushort2v;

__device__ __forceinline__ float wmaxred(float v) {
#pragma unroll
  for (int off = 32; off > 0; off >>= 1) v = fmaxf(v, __shfl_xor(v, off, 64));
  return v;
}
__device__ __forceinline__ float wsumred(float v) {
#pragma unroll
  for (int off = 32; off > 0; off >>= 1) v += __shfl_xor(v, off, 64);
  return v;
}

// L2-coherent (XCD-scope) primitives: sc0 = bypass L1, hit/write the XCD's L2.
// "=&v" early-clobber: result must not alias the address pair (round-5 hang).
__device__ __forceinline__ unsigned long long load_u64_l2(const unsigned long long* a) {
  unsigned long long w;
  asm volatile("global_load_dwordx2 %0, %1, off sc0\n\ts_waitcnt vmcnt(0)"
               : "=&v"(w) : "v"(a) : "memory");
  return w;
}
__device__ __forceinline__ void store_u32_l2(unsigned* p, unsigned v) {
  asm volatile("global_store_dword %0, %1, off sc0" ::"v"(p), "v"(v) : "memory");
}
// Tight self-validating poll (no sleep — round-7 showed backoff serializes the
// straggler cascade); permanent agent-scope fallback after ESC_SPINS.
__device__ __forceinline__ unsigned long long poll_u64(const unsigned long long* a,
                                                       unsigned tag, bool& esc) {
  const unsigned long long pat =
      ((unsigned long long)tag << 16) | ((unsigned long long)tag << 48);
  const unsigned long long msk = 0xFFFF0000FFFF0000ULL;
  unsigned long long w;
  int spins = 0;
  for (;;) {
    w = esc ? __hip_atomic_load(a, __ATOMIC_RELAXED, AGENT) : load_u64_l2(a);
    if ((w & msk) == pat) return w;
    if (!esc && ++spins >= ESC_SPINS) esc = true;
  }
}

__device__ __forceinline__ float f16v(unsigned short b) {
  return (float)__builtin_bit_cast(_Float16, b);
}
__device__ __forceinline__ unsigned short f16b(float f) {
  return __builtin_bit_cast(unsigned short, (_Float16)f);
}

// One-time: Et[j][i] = exp(trans[i][j])  (transposed, fp16) via LDS tile transpose.
__global__ void prep_E(const float* __restrict__ trans, _Float16* __restrict__ Et) {
  __shared__ float tile[32][33];
  const int tx = threadIdx.x, ty = threadIdx.y;
  const int bi = blockIdx.y, bj = blockIdx.x;
  tile[ty][tx] = trans[(size_t)(bi * 32 + ty) * S + bj * 32 + tx];
  __syncthreads();
  Et[(size_t)(bj * 32 + ty) * S + bi * 32 + tx] = (_Float16)__expf(tile[tx][ty]);
}

// One-time: emitT[o][j] = emit[j][o] (fp16). Per step all 1024 emit values are
// then one contiguous 2 KB row (16 lines) instead of 1024 scattered lines.
__global__ void prep_emitT(const float* __restrict__ emit, _Float16* __restrict__ emitT) {
  __shared__ float tile[32][33];
  const int tx = threadIdx.x, ty = threadIdx.y;
  const int bj = blockIdx.y, bo = blockIdx.x;  // bj over S/32, bo over NOBS/32
  tile[ty][tx] = emit[(size_t)(bj * 32 + ty) * NOBS + bo * 32 + tx];
  __syncthreads();
  emitT[(size_t)(bo * 32 + ty) * S + bj * 32 + tx] = (_Float16)tile[tx][ty];
}

// One-time: r0 = start + emit[:, obs[0]] packed {tag=0|fp16}; election state reset.
__global__ void hmm_init(const int* __restrict__ obs, const float* __restrict__ start,
                         const float* __restrict__ emit, unsigned* rbuf, int* ctrl) {
  const int tid = threadIdx.x;  // 1024 threads
  const float r = start[tid] + emit[(size_t)tid * NOBS + obs[0]];
  rbuf[tid] = (unsigned)f16b(r);  // tag 0 in hi16
  if (tid < 8) ctrl[tid] = 0;     // per-XCD arrival counters
  if (tid == 8) ctrl[8] = -1;     // winner XCD
}

__global__ __launch_bounds__(NTHR) void hmm_main(
    const int* __restrict__ obs, const _Float16* __restrict__ emitT,
    const _Float16* __restrict__ Et, unsigned* rbuf, int* ctrl,
    float* __restrict__ out) {
  __shared__ unsigned sp[2][S / 2];  // p packed half2, double-buffered (4 KB)
  __shared__ float wred[NWAVE];
  __shared__ int s_rank;
  const int tid = threadIdx.x;
  const int lane = tid & 63;
  const int wave = tid >> 6;

  // ---- election: the 16 first-arriving WGs on one XCD participate ----
  if (tid == 0) {
    int x;
    asm volatile("s_getreg_b32 %0, hwreg(HW_REG_XCC_ID)" : "=s"(x));
    x &= 7;
    const int r = atomicAdd(&ctrl[x], 1);  // device-scope
    int wnr = -2;
    if (r == NEED - 1) atomicCAS(&ctrl[8], -1, x);
    if (r < NEED) {
      while ((wnr = __hip_atomic_load(&ctrl[8], __ATOMIC_RELAXED, AGENT)) == -1)
        __builtin_amdgcn_s_sleep(8);
    }
    s_rank = (wnr == x) ? r : -1;
  }
  __syncthreads();
  const int rank = s_rank;
  if (rank < 0) return;

  const int c0 = rank * COLS + wave * CPW;  // this wave's 8 output columns
  bool esc = false;

  // E fragments in registers: er[c][k] covers sources {k*128 + 2*lane, +1} for
  // column c0+c. 64 packed-fp16 VGPRs.
  half2v er[CPW][8];
#pragma unroll
  for (int c = 0; c < CPW; ++c)
#pragma unroll
    for (int k = 0; k < 8; ++k)
      er[c][k] = *(const half2v*)(Et + (size_t)(c0 + c) * S + k * 128 + lane * 2);

  // ---- emit prefetch pipeline on emitT (8 steps/fetch, double-buffered) ----
  // Lane L carries e for step-offset L>>3, column c0+(L&7): one coalesced
  // 16 B/8-lane-group load per wave per 8 steps, consumed 8..16 steps later.
  const int pfoff = lane >> 3;       // 0..7 step offset within group
  const int pfcol = c0 + (lane & 7); // emitT column
  float curE, nxtE;
  curE = (float)emitT[(size_t)obs[1 + pfoff] * S + pfcol];
  nxtE = (float)emitT[(size_t)obs[9 + pfoff] * S + pfcol];

  unsigned long long* const b0 = (unsigned long long*)rbuf;        // even t
  unsigned long long* const b1 = (unsigned long long*)(rbuf + S);  // odd t

  // Preamble: fresh m = max(r_0), identical in every thread/WG.
  {
    const unsigned long long w = poll_u64(b0 + tid, 0u, esc);
    const float wm =
        wmaxred(fmaxf(f16v((unsigned short)w), f16v((unsigned short)(w >> 32))));
    if (lane == 0) wred[wave] = wm;
  }
  __syncthreads();
  float m = wred[0];
#pragma unroll
  for (int k = 1; k < NWAVE; ++k) m = fmaxf(m, wred[k]);

  double c = 0.0;  // accumulated scale offset; identical in every thread
  for (int t = 1; t < TSTEPS; ++t) {
    const int s = (t - 1) & 7;
    if (s == 0 && t > 1) {  // rotate prefetch buffers, fetch group [t+8, t+16)
      curE = nxtE;
      const int oi = obs[min(t + 8 + pfoff, TSTEPS - 1)];
      nxtE = (float)emitT[(size_t)oi * S + pfcol];
    }
    // e for this lane's column c0+(lane&7) at step t — one shuffle, no memory
    const float ecol = __shfl(curE, s * 8 + (lane & 7));

    // poll own u64 of r_{t-1} (slots 2*tid, 2*tid+1) from the XCD-local L2
    const unsigned long long w =
        poll_u64(((t & 1) ? b0 : b1) + tid, (unsigned)(t - 1), esc);
    half2v ph;
    ph[0] = (_Float16)__expf(f16v((unsigned short)w) - m);
    ph[1] = (_Float16)__expf(f16v((unsigned short)(w >> 32)) - m);
    sp[t & 1][tid] = __builtin_bit_cast(unsigned, ph);
    __syncthreads();  // the only barrier per step

    // dot: 8 conflict-free LDS b32 reads, 64 fdot2; packed max(p) alongside
    const unsigned* pb = sp[t & 1];
    float a[CPW] = {0.f, 0.f, 0.f, 0.f, 0.f, 0.f, 0.f, 0.f};
    ushort2v mx = {0, 0};
#pragma unroll
    for (int k = 0; k < 8; ++k) {
      const unsigned pw = pb[k * 64 + lane];
      mx = __builtin_elementwise_max(mx, __builtin_bit_cast(ushort2v, pw));
      const half2v pv = __builtin_bit_cast(half2v, pw);
#pragma unroll
      for (int ci = 0; ci < CPW; ++ci)
        a[ci] = __builtin_amdgcn_fdot2(pv, er[ci][k], a[ci], false);
    }

    // transpose-reduce: 3 butterflies x 8 accs -> select -> 3 butterflies.
    // Ends with lane L holding the full sum for column c0+(L&7).
#pragma unroll
    for (int off = 1; off <= 4; off <<= 1) {
#pragma unroll
      for (int ci = 0; ci < CPW; ++ci) a[ci] += __shfl_xor(a[ci], off, 64);
    }
    const int idx = lane & 7;
    const float s01 = (idx & 1) ? a[1] : a[0], s23 = (idx & 1) ? a[3] : a[2];
    const float s45 = (idx & 1) ? a[5] : a[4], s67 = (idx & 1) ? a[7] : a[6];
    const float u0 = (idx & 2) ? s23 : s01, u1 = (idx & 2) ? s67 : s45;
    float v = (idx & 4) ? u1 : u0;
#pragma unroll
    for (int off = 8; off <= 32; off <<= 1) v += __shfl_xor(v, off, 64);

    // publish: lanes 0..7 store their own tagged u32 (coalesced 32 B, sc0)
    const unsigned myw = ((unsigned)t << 16) | f16b(__logf(v) + ecol);
    if (lane < CPW) store_u32_l2(rbuf + (t & 1) * S + c0 + lane, myw);

    // off the critical path: scale bookkeeping and next step's stale m
    c += (double)m;
#pragma unroll
    for (int off = 32; off > 0; off >>= 1) {
      const unsigned o2 = __shfl_xor(__builtin_bit_cast(unsigned, mx), off, 64);
      mx = __builtin_elementwise_max(mx, __builtin_bit_cast(ushort2v, o2));
    }
    const unsigned short ms = mx[0] > mx[1] ? mx[0] : mx[1];  // positive fp16: bit order = value order
    m += __logf(f16v(ms));  // m = max(r_{t-1}); bit-identical in every wave/WG
  }

  // Final logsumexp over r_{T-1} by rank 0, wave 0 (8 u64/lane covers all 1024).
  if (rank == 0 && wave == 0) {
    const unsigned long long* src = b1 + lane * 8;  // 8191 is odd
    float v[16];
#pragma unroll
    for (int j = 0; j < 8; ++j) {
      const unsigned long long w = poll_u64(&src[j], TSTEPS - 1, esc);
      v[2 * j] = f16v((unsigned short)w);
      v[2 * j + 1] = f16v((unsigned short)(w >> 32));
    }
    float g = -1e30f;
#pragma unroll
    for (int j = 0; j < 16; ++j) g = fmaxf(g, v[j]);
    g = wmaxred(g);
    float s = 0.f;
#pragma unroll
    for (int j = 0; j < 16; ++j) s += __expf(v[j] - g);
    s = wsumred(s);
    if (lane == 0) out[0] = (float)(c + (double)g + (double)__logf(s));
  }
}

extern "C" void kernel_launch(void* const* d_in, const int* in_sizes, int n_in,
                              void* d_out, int out_size, void* d_ws, size_t ws_size,
                              hipStream_t stream) {
  const int* obs = (const int*)d_in[0];
  const float* start = (const float*)d_in[1];
  const float* trans = (const float*)d_in[2];
  const float* emit = (const float*)d_in[3];

  // ws: 0: rbuf[2][1024] u32 (8 KB) | 12288: ctrl[9] | 16384: Et (2 MB) |
  //     16384+2M: emitT 4096*1024 fp16 (8 MB)
  unsigned* rbuf = (unsigned*)d_ws;
  int* ctrl = (int*)((char*)d_ws + 12288);
  _Float16* Et = (_Float16*)((char*)d_ws + 16384);
  _Float16* emitT = (_Float16*)((char*)d_ws + 16384 + (size_t)2 * 1024 * 1024);

  prep_E<<<dim3(32, 32), dim3(32, 32), 0, stream>>>(trans, Et);
  prep_emitT<<<dim3(NOBS / 32, S / 32), dim3(32, 32), 0, stream>>>(emit, emitT);
  hmm_init<<<1, S, 0, stream>>>(obs, start, emit, rbuf, ctrl);
  hmm_main<<<NLAUNCH, NTHR, 0, stream>>>(obs, emitT, Et, rbuf, ctrl, (float*)d_out);
}